// Round 9
// baseline (66.645 us; speedup 1.0000x reference)
//
#include <hip/hip_runtime.h>

// DifferentiableCIndexLoss:
//   mask[i,j] = (t[i] < t[j]) && (e[i]==1)
//   loss = sum sigmoid((r[j]-r[i])/SIGMA) * mask ;  count = sum mask
//   out  = loss / (count + 1e-6)
//
// R9 = R8 with k_main inner loop rebuilt for LDS-latency tolerance:
//   - SoA tiles (tileF/tileT): hot loop reads float4 (4 cols / ds_read_b128),
//     16 sigmoids (~192 cyc compute) per ~120-cyc-latency LDS read.
//     (R8 read 1 col/ds_read_b32 -> 48 cyc compute per 120 cyc latency; k_main
//     stalled ~4x at VALUBusy ~12%.)
//   - k_scatter column-sum loop unrolled x8 for MLP (64 blocks = 1/CU, no TLP).
// Pipeline (4 nodes, no device-scope atomics/fences/spins -- R4-R7 lesson):
//  1) k_hist    (64 blk): per-block LDS hist slices (pure overwrite).
//  2) k_scatter (64 blk): redundant column-sum+scan per block -> scatter via
//                LDS cursors; block 0 writes chunk/page bucket bounds.
//  3) k_main  (2048 blk): chunk=256 rows held by each wave (4/lane); 8 pages
//                staged in LDS (SoA); waves own disjoint pages. all-false
//                skip / all-true fma+rcp+add + analytic count / mixed exact.
//  4) k_finalize (1 blk): double-precision reduce, out = L/(C+1e-6).
// Exactness: bucket monotone in t => strict bucket inequality proves the
// compare; overlapping-bucket tiles use exact per-pair compares. Count exact.
//   sigmoid((r_j-r_i)/sigma) = 1/(1 + 2^{s_i} 2^{-s_j}), s=r*log2e/sigma,
//   |s|<=60 so the product is in [2^-120,2^120]: no overflow/NaN.

#define NB 1024
#define BLOCK 256
#define NBLK_DATA 64               // 16384/256
#define RC_SHIFT 8                 // 256 rows per chunk
#define MAXRC 64
#define JP_SHIFT 6                 // 64 cols per page
#define MAXPG 256
#define GRID_MAIN (MAXRC * 32)     // 2048

__device__ __forceinline__ float fast_exp2(float x) { return __builtin_amdgcn_exp2f(x); }
__device__ __forceinline__ float fast_rcp(float x)  { return __builtin_amdgcn_rcpf(x); }
__device__ __forceinline__ float clamp60(float x)   { return fminf(fmaxf(x, -60.0f), 60.0f); }
__device__ __forceinline__ int bucket_of(float tv) {
    int b = (int)(tv * (float)NB);
    return min(max(b, 0), NB - 1);
}
#define SIG(e, f) fast_rcp(__builtin_fmaf((e), (f), 1.0f))

// ---- 1) per-block histogram slices ------------------------------------------
__global__ __launch_bounds__(BLOCK) void k_hist(
    const float* __restrict__ t, const int* __restrict__ ev,
    int* __restrict__ hIb, int* __restrict__ hJb) {
    __shared__ int hI[NB], hJ[NB];
    const int tid = threadIdx.x, b = blockIdx.x;
    for (int i = tid; i < NB; i += BLOCK) { hI[i] = 0; hJ[i] = 0; }
    __syncthreads();
    int g = (b << 8) + tid;
    int bk = bucket_of(t[g]);
    atomicAdd(&hJ[bk], 1);
    if (ev[g] == 1) atomicAdd(&hI[bk], 1);
    __syncthreads();
    int* oI = hIb + b * NB;
    int* oJ = hJb + b * NB;
    for (int i = tid; i < NB; i += BLOCK) { oI[i] = hI[i]; oJ[i] = hJ[i]; }
}

// ---- 2) scan (redundant per block) + bounds + scatter -----------------------
__global__ __launch_bounds__(BLOCK) void k_scatter(
    const float* __restrict__ r, const float* __restrict__ t,
    const int* __restrict__ ev, float kscale,
    const int* __restrict__ hIb, const int* __restrict__ hJb,
    int* __restrict__ rcLo, int* __restrict__ rcHi,
    int* __restrict__ jpLo, int* __restrict__ jpHi,
    int* __restrict__ nactive_g,
    float2* __restrict__ sI, float2* __restrict__ sJ) {

    const int tid = threadIdx.x, b = blockIdx.x;
    __shared__ int ps[2 * BLOCK];
    __shared__ int baseI[NB], baseJ[NB];
    __shared__ int rcLo_s[MAXRC], rcHi_s[MAXRC], jpLo_s[MAXPG], jpHi_s[MAXPG];
    const int bk0 = tid << 2;                 // 4 contiguous buckets per thread

    // column totals over 64 slices + prefix over blocks < b (unrolled for MLP:
    // 64 blocks = 1 block/CU, no TLP -- need many loads in flight)
    int tI[4] = {0,0,0,0}, tJ[4] = {0,0,0,0};
    int pI[4] = {0,0,0,0}, pJ[4] = {0,0,0,0};
#pragma unroll 8
    for (int bb = 0; bb < NBLK_DATA; ++bb) {
        int4 vI = *(const int4*)(hIb + bb * NB + bk0);
        int4 vJ = *(const int4*)(hJb + bb * NB + bk0);
        tI[0] += vI.x; tI[1] += vI.y; tI[2] += vI.z; tI[3] += vI.w;
        tJ[0] += vJ.x; tJ[1] += vJ.y; tJ[2] += vJ.z; tJ[3] += vJ.w;
        int take = (bb < b) ? 1 : 0;
        pI[0] += take * vI.x; pI[1] += take * vI.y; pI[2] += take * vI.z; pI[3] += take * vI.w;
        pJ[0] += take * vJ.x; pJ[1] += take * vJ.y; pJ[2] += take * vJ.z; pJ[3] += take * vJ.w;
    }
    int sIt = (tI[0] + tI[1]) + (tI[2] + tI[3]);
    int sJt = (tJ[0] + tJ[1]) + (tJ[2] + tJ[3]);
    ps[tid] = sIt; ps[BLOCK + tid] = sJt;
    __syncthreads();
    for (int off = 1; off < BLOCK; off <<= 1) {       // dual Hillis-Steele
        int a = (tid >= off) ? ps[tid - off] : 0;
        int c = (tid >= off) ? ps[BLOCK + tid - off] : 0;
        __syncthreads();
        ps[tid] += a; ps[BLOCK + tid] += c;
        __syncthreads();
    }
    int exI = ps[tid] - sIt, exJ = ps[BLOCK + tid] - sJt;
    int eI[4], eJ[4];
    { int runI = exI, runJ = exJ;
#pragma unroll
      for (int k = 0; k < 4; ++k) { eI[k] = runI; runI += tI[k]; eJ[k] = runJ; runJ += tJ[k]; } }

    if (b == 0 && tid == BLOCK - 1) *nactive_g = ps[BLOCK - 1];

    if (b == 0) {   // chunk/page bucket bounds (block-uniform branch)
        if (tid < MAXRC) { rcLo_s[tid] = 0x7fffffff; rcHi_s[tid] = -1; }
        if (tid < MAXPG) { jpLo_s[tid] = 0x7fffffff; jpHi_s[tid] = -1; }
        __syncthreads();
#pragma unroll
        for (int k = 0; k < 4; ++k) {
            int bk = bk0 + k;
            if (tI[k] > 0) {
                int c0 = eI[k] >> RC_SHIFT, c1 = (eI[k] + tI[k] - 1) >> RC_SHIFT;
                for (int c = c0; c <= c1; ++c) { atomicMin(&rcLo_s[c], bk); atomicMax(&rcHi_s[c], bk); }
            }
            if (tJ[k] > 0) {
                int c0 = eJ[k] >> JP_SHIFT, c1 = (eJ[k] + tJ[k] - 1) >> JP_SHIFT;
                for (int c = c0; c <= c1; ++c) { atomicMin(&jpLo_s[c], bk); atomicMax(&jpHi_s[c], bk); }
            }
        }
        __syncthreads();
        if (tid < MAXRC) { rcLo[tid] = rcLo_s[tid]; rcHi[tid] = rcHi_s[tid]; }
        if (tid < MAXPG) { jpLo[tid] = jpLo_s[tid]; jpHi[tid] = jpHi_s[tid]; }
    }

    // per-bucket cursors for THIS block = global excl + prefix of earlier blocks
#pragma unroll
    for (int k = 0; k < 4; ++k) {
        baseI[bk0 + k] = eI[k] + pI[k];
        baseJ[bk0 + k] = eJ[k] + pJ[k];
    }
    __syncthreads();

    // scatter my element
    int g = (b << 8) + tid;
    float tv = t[g];
    float s  = clamp60(r[g] * kscale);
    int bk = bucket_of(tv);
    int pj = atomicAdd(&baseJ[bk], 1);
    sJ[pj] = make_float2(fast_exp2(-s), tv);
    if (ev[g] == 1) {
        int pi = atomicAdd(&baseI[bk], 1);
        sI[pi] = make_float2(fast_exp2(s), tv);
    }
}

// ---- 3) main: classified tiles, SoA LDS, float4 reads -----------------------
__global__ __launch_bounds__(BLOCK) void k_main(
    const float2* __restrict__ sI, const float2* __restrict__ sJ,
    const int* __restrict__ rcLo, const int* __restrict__ rcHi,
    const int* __restrict__ jpLo, const int* __restrict__ jpHi,
    const int* __restrict__ nactive_g,
    float* __restrict__ pL, unsigned int* __restrict__ pC) {

    const int tid = threadIdx.x;
    const int rc = blockIdx.x & (MAXRC - 1);
    const int psIdx = blockIdx.x >> 6;        // 0..31
    const int wid = tid >> 6, lane = tid & 63;
    const int nactive = *nactive_g;
    const int rl = rcLo[rc], rh = rcHi[rc];

    __shared__ float tileF[8][64];            // SoA: 4 cols per ds_read_b128
    __shared__ float tileT[8][64];
    for (int e = tid; e < 512; e += BLOCK) {
        int m = e >> 6, jj = e & 63;
        float2 q = sJ[((psIdx + (m << 5)) << 6) + jj];
        tileF[m][jj] = q.x;
        tileT[m][jj] = q.y;
    }

    // my wave holds the whole 256-row chunk: 4 rows per lane
    float E[4], T[4];
    int nv = 0;
    const int rbase = rc << RC_SHIFT;
#pragma unroll
    for (int k = 0; k < 4; ++k) {
        int rr = rbase + lane + (k << 6);
        if (rr < nactive) { float2 f = sI[rr]; E[k] = f.x; T[k] = f.y; ++nv; }
        else              { E[k] = __builtin_inff(); T[k] = 3.0f; }  // 0 contrib
    }
    __syncthreads();

    float lsum = 0.0f;
    int   csum = 0;

#pragma unroll
    for (int mi = 0; mi < 2; ++mi) {
        int m = wid + (mi << 2);              // waves own disjoint pages
        int p = psIdx + (m << 5);
        int jh = jpHi[p];
        if (rl > jh) continue;                // all-false (or empty chunk)
        int jl = jpLo[p];
        const float4* Fq = (const float4*)&tileF[m][0];

        if (rh < jl) {                        // all-true: no compare
            float l[4] = {0.f, 0.f, 0.f, 0.f};
#pragma unroll 4
            for (int q4 = 0; q4 < 16; ++q4) {
                float4 Fv = Fq[q4];           // 4 cols per LDS read
                float fc[4] = {Fv.x, Fv.y, Fv.z, Fv.w};
#pragma unroll
                for (int c4 = 0; c4 < 4; ++c4) {
#pragma unroll
                    for (int k = 0; k < 4; ++k)
                        l[k] += SIG(E[k], fc[c4]);
                }
            }
            lsum += (l[0] + l[1]) + (l[2] + l[3]);
            csum += nv << 6;                  // analytic count
        } else {                              // mixed: exact per-pair compare
            const float4* Tq = (const float4*)&tileT[m][0];
            float l[4] = {0.f, 0.f, 0.f, 0.f};
            int c = 0;
#pragma unroll 2
            for (int q4 = 0; q4 < 16; ++q4) {
                float4 Fv = Fq[q4];
                float4 Tv = Tq[q4];
                float fc[4] = {Fv.x, Fv.y, Fv.z, Fv.w};
                float tc[4] = {Tv.x, Tv.y, Tv.z, Tv.w};
#pragma unroll
                for (int c4 = 0; c4 < 4; ++c4) {
#pragma unroll
                    for (int k = 0; k < 4; ++k) {
                        float sg = SIG(E[k], fc[c4]);
                        bool mm = T[k] < tc[c4];
                        l[k] += mm ? sg : 0.0f;
                        c += mm;
                    }
                }
            }
            lsum += (l[0] + l[1]) + (l[2] + l[3]);
            csum += c;
        }
    }

    // block reduce + PLAIN partial stores (no device-scope atomics/fences)
#pragma unroll
    for (int off = 32; off > 0; off >>= 1) {
        lsum += __shfl_down(lsum, off);
        csum += __shfl_down(csum, off);
    }
    __shared__ float lw[BLOCK / 64];
    __shared__ int   cw[BLOCK / 64];
    if ((tid & 63) == 0) { lw[wid] = lsum; cw[wid] = csum; }
    __syncthreads();
    if (tid == 0) {
        pL[blockIdx.x] = (lw[0] + lw[1]) + (lw[2] + lw[3]);
        pC[blockIdx.x] = (unsigned)((cw[0] + cw[1]) + (cw[2] + cw[3]));
    }
}

// ---- 4) finalize --------------------------------------------------------------
__global__ __launch_bounds__(BLOCK) void k_finalize(
    const float* __restrict__ pL, const unsigned int* __restrict__ pC,
    int n, float* __restrict__ out) {
    double l = 0.0, c = 0.0;
    for (int i = threadIdx.x; i < n; i += BLOCK) {
        l += (double)pL[i];
        c += (double)pC[i];
    }
#pragma unroll
    for (int off = 32; off > 0; off >>= 1) {
        l += __shfl_down(l, off);
        c += __shfl_down(c, off);
    }
    __shared__ double lw[BLOCK / 64], cw[BLOCK / 64];
    int wid = threadIdx.x >> 6;
    if ((threadIdx.x & 63) == 0) { lw[wid] = l; cw[wid] = c; }
    __syncthreads();
    if (threadIdx.x == 0) {
        double L = (lw[0] + lw[1]) + (lw[2] + lw[3]);
        double C = (cw[0] + cw[1]) + (cw[2] + cw[3]);
        out[0] = (float)(L / (C + 1e-6));
    }
}

extern "C" void kernel_launch(void* const* d_in, const int* in_sizes, int n_in,
                              void* d_out, int out_size, void* d_ws, size_t ws_size,
                              hipStream_t stream) {
    const float* r  = (const float*)d_in[0];
    const float* t  = (const float*)d_in[1];
    const int*   ev = (const int*)d_in[2];
    float* out = (float*)d_out;
    const int B = in_sizes[0];   // 16384

    const float SIGMA = 0.1f;
    const float LOG2E = 1.4426950408889634f;
    const float kscale = LOG2E / SIGMA;

    char* ws = (char*)d_ws;
    int* rcLo = (int*)(ws + 0);          // 64 ints
    int* rcHi = (int*)(ws + 256);        // 64 ints
    int* jpLo = (int*)(ws + 512);        // 256 ints
    int* jpHi = (int*)(ws + 1536);       // 256 ints
    int* nactive_g = (int*)(ws + 2560);
    int* hIb   = (int*)(ws + 4096);                       // 64*1024*4 = 256 KB
    int* hJb   = (int*)(ws + 4096 + 262144);              // 256 KB
    float2* sI = (float2*)(ws + 4096 + 524288);           // 128 KB
    float2* sJ = (float2*)(ws + 4096 + 524288 + 131072);  // 128 KB
    float*  pL = (float*)(ws + 4096 + 524288 + 262144);
    unsigned int* pC = (unsigned int*)((char*)pL + (size_t)GRID_MAIN * 4);

    k_hist<<<NBLK_DATA, BLOCK, 0, stream>>>(t, ev, hIb, hJb);
    k_scatter<<<NBLK_DATA, BLOCK, 0, stream>>>(r, t, ev, kscale, hIb, hJb,
        rcLo, rcHi, jpLo, jpHi, nactive_g, sI, sJ);
    k_main<<<GRID_MAIN, BLOCK, 0, stream>>>(sI, sJ, rcLo, rcHi, jpLo, jpHi,
        nactive_g, pL, pC);
    k_finalize<<<1, BLOCK, 0, stream>>>(pL, pC, GRID_MAIN, out);
}

// Round 10
// 42.116 us; speedup vs baseline: 1.5824x; 1.5824x over previous
//
#include <hip/hip_runtime.h>

// DifferentiableCIndexLoss:
//   mask[i,j] = (t[i] < t[j]) && (e[i]==1)
//   loss = sum sigmoid((r[j]-r[i])/SIGMA) * mask ;  count = sum mask
//   out  = loss / (count + 1e-6)
//
// R10: consolidation on the PROVEN R3 structure (best: 48.5us). Sorted-
// classification branch abandoned (R4-R9: never beat R3, undiagnosed stalls).
// Changes vs R3, each attacking a measured overhead of R3's main (~32us vs
// 15.4us issue floor):
//   - compact kernel PRE-TRANSFORMS rows: sI[i]=(2^{s_i}, t_i) packed float2
//     (was: per-tile idx->t->r gather chain + exp2 in main = 24 loads/256
//     pairs). k_main row load = 4 coalesced float2 loads, once per tile.
//   - cols pre-transformed too: sJ[j]=(2^{-s_j}, t_j); main's inner loop is
//     fma+rcp+cmp+cndmask+add+addc = 6 ops/pair, ONE transcendental.
//   - JTILE=64 staged once per tile (512B LDS), wave-uniform broadcast reads
//     (R2-proven; NOT shfl (R6 lesson), NOT float4 SoA (R9 lesson)).
//   - plain partial stores + tiny finalize (R8 lesson: no device-scope
//     atomics/fences/spins in hot kernels).
//   sigmoid((r_j-r_i)/sigma) = 1/(1 + 2^{s_i} 2^{-s_j}), s=r*log2e/sigma,
//   |s|<=60 so the product is in [2^-120,2^120]: no overflow/NaN.

#define BLOCK 256
#define RPT 4                        // rows per thread
#define ROWS_PER_TILE (BLOCK * RPT)  // 1024
#define JTILE 64                     // cols per tile
#define NCOLGRP 256                  // 16384/64
#define GRID_MAIN 2048

__device__ __forceinline__ float fast_exp2(float x) { return __builtin_amdgcn_exp2f(x); }
__device__ __forceinline__ float fast_rcp(float x)  { return __builtin_amdgcn_rcpf(x); }
__device__ __forceinline__ float clamp60(float x)   { return fminf(fmaxf(x, -60.0f), 60.0f); }

// ---- 1) transform cols + ballot-compact active rows (pre-transformed) -------
__global__ __launch_bounds__(BLOCK) void k_compact(
    const float* __restrict__ r, const float* __restrict__ t,
    const int* __restrict__ ev, int B, float kscale,
    int* __restrict__ cursor,          // zeroed by memset; final value = nactive
    float2* __restrict__ sI, float2* __restrict__ sJ) {
    int g = blockIdx.x * BLOCK + threadIdx.x;
    if (g >= B) return;
    float tv = t[g];
    float s  = clamp60(r[g] * kscale);
    sJ[g] = make_float2(fast_exp2(-s), tv);        // F_j = 2^{-s_j}
    bool pred = (ev[g] == 1);
    unsigned long long m = __ballot(pred);
    int lane = threadIdx.x & 63;
    int before = __popcll(m & ((1ull << lane) - 1ull));
    int total = __popcll(m);
    int base = 0;
    if (lane == 0 && total > 0) base = atomicAdd(cursor, total);
    base = __shfl(base, 0);
    if (pred) sI[base + before] = make_float2(fast_exp2(s), tv);   // E_i = 2^{s_i}
}

// ---- 2) main: all-pairs over compacted rows, grid-stride device ntiles ------
__global__ __launch_bounds__(BLOCK) void k_main(
    const float2* __restrict__ sI, const float2* __restrict__ sJ,
    const int* __restrict__ nactive_g,
    float* __restrict__ pL, unsigned int* __restrict__ pC) {

    const int tid = threadIdx.x;
    const int nactive = *nactive_g;
    const int nrc = (nactive + ROWS_PER_TILE - 1) / ROWS_PER_TILE;  // ~8
    const int ntiles = nrc * NCOLGRP;                                // ~2048

    __shared__ float2 tile[JTILE];

    float lsum = 0.0f;
    int   csum = 0;

    for (int tix = blockIdx.x; tix < ntiles; tix += gridDim.x) {
        int rc = tix >> 8;            // row chunk (ntiles = nrc*256)
        int cg = tix & (NCOLGRP - 1); // col group

        // 4 rows/thread, coalesced float2 loads, once per tile
        float E[RPT], T[RPT];
        int rbase = rc * ROWS_PER_TILE;
#pragma unroll
        for (int k = 0; k < RPT; ++k) {
            int rr = rbase + tid + (k << 8);
            if (rr < nactive) { float2 f = sI[rr]; E[k] = f.x; T[k] = f.y; }
            else              { E[k] = __builtin_inff(); T[k] = 3.0f; }
            // inf row: rcp(1+inf*F)=0 contribution; t=3 -> mask never fires
        }

        __syncthreads();              // protect tile[] from previous iteration
        if (tid < JTILE) tile[tid] = sJ[(cg << 6) + tid];
        __syncthreads();

        float l[RPT] = {0.f, 0.f, 0.f, 0.f};
        int c = 0;
#pragma unroll 8
        for (int jj = 0; jj < JTILE; ++jj) {
            float2 q = tile[jj];      // wave-uniform LDS broadcast
            float F = q.x, tj = q.y;
#pragma unroll
            for (int k = 0; k < RPT; ++k) {
                float sg = fast_rcp(__builtin_fmaf(E[k], F, 1.0f));
                bool m = T[k] < tj;
                l[k] += m ? sg : 0.0f;
                c += m;
            }
        }
        lsum += (l[0] + l[1]) + (l[2] + l[3]);
        csum += c;
    }

    // block reduce + plain partial stores
#pragma unroll
    for (int off = 32; off > 0; off >>= 1) {
        lsum += __shfl_down(lsum, off);
        csum += __shfl_down(csum, off);
    }
    __shared__ float lw[BLOCK / 64];
    __shared__ int   cw[BLOCK / 64];
    int wid = tid >> 6;
    if ((tid & 63) == 0) { lw[wid] = lsum; cw[wid] = csum; }
    __syncthreads();
    if (tid == 0) {
        pL[blockIdx.x] = (lw[0] + lw[1]) + (lw[2] + lw[3]);
        pC[blockIdx.x] = (unsigned)((cw[0] + cw[1]) + (cw[2] + cw[3]));
    }
}

// ---- 3) finalize -------------------------------------------------------------
__global__ __launch_bounds__(BLOCK) void k_finalize(
    const float* __restrict__ pL, const unsigned int* __restrict__ pC,
    int n, float* __restrict__ out) {
    double l = 0.0, c = 0.0;
    for (int i = threadIdx.x; i < n; i += BLOCK) {
        l += (double)pL[i];
        c += (double)pC[i];
    }
#pragma unroll
    for (int off = 32; off > 0; off >>= 1) {
        l += __shfl_down(l, off);
        c += __shfl_down(c, off);
    }
    __shared__ double lw[BLOCK / 64], cw[BLOCK / 64];
    int wid = threadIdx.x >> 6;
    if ((threadIdx.x & 63) == 0) { lw[wid] = l; cw[wid] = c; }
    __syncthreads();
    if (threadIdx.x == 0) {
        double L = (lw[0] + lw[1]) + (lw[2] + lw[3]);
        double C = (cw[0] + cw[1]) + (cw[2] + cw[3]);
        out[0] = (float)(L / (C + 1e-6));
    }
}

extern "C" void kernel_launch(void* const* d_in, const int* in_sizes, int n_in,
                              void* d_out, int out_size, void* d_ws, size_t ws_size,
                              hipStream_t stream) {
    const float* r  = (const float*)d_in[0];
    const float* t  = (const float*)d_in[1];
    const int*   ev = (const int*)d_in[2];
    float* out = (float*)d_out;
    const int B = in_sizes[0];   // 16384

    const float SIGMA = 0.1f;
    const float LOG2E = 1.4426950408889634f;
    const float kscale = LOG2E / SIGMA;

    char* ws = (char*)d_ws;
    int* cursor = (int*)ws;                        // [0,64): atomic cursor = nactive
    float2* sI  = (float2*)(ws + 4096);            // 128 KB (compacted rows: E, t)
    float2* sJ  = sI + B;                          // 128 KB (all cols: F, t)
    float*  pL  = (float*)(sJ + B);
    unsigned int* pC = (unsigned int*)(pL + GRID_MAIN);

    const int nblk = (B + BLOCK - 1) / BLOCK;      // 64

    hipMemsetAsync(ws, 0, 64, stream);
    k_compact<<<nblk, BLOCK, 0, stream>>>(r, t, ev, B, kscale, cursor, sI, sJ);
    k_main<<<GRID_MAIN, BLOCK, 0, stream>>>(sI, sJ, cursor, pL, pC);
    k_finalize<<<1, BLOCK, 0, stream>>>(pL, pC, GRID_MAIN, out);
}